// Round 7
// baseline (29.407 us; speedup 1.0000x reference)
//
#include <hip/hip_runtime.h>

#define N 2048
#define BATCH 32
#define BLOCK 256
#define SLICES 64                  // blocks per batch row
#define I_PER_BLOCK (N / SLICES)   // 32 output elements per block
#define SUBS 8                     // threads cooperating per output i

typedef float v2f __attribute__((ext_vector_type(2)));

// All-polynomial exp: e^{x_i x_j/16} = (e^u)^8, u = x_i x_j/128, |u|<=0.16.
// Deg-4 Taylor (rel err 8e-7, x8 after 3 squarings -> 7e-6) runs entirely on
// the packed-f32 VALU pipe — zero v_exp_f32. R2-R6 data fits a sum-model
// where each trans wave-instr costs ~20 cyc of SIMD issue occupancy
// (2048/SIMD x 20 = 41K cyc = the 17us plateau); poly is 20 pk-instr/float4
// = 20.5K cyc/SIMD. No max-subtraction (args bounded, scale cancels).
__global__ __launch_bounds__(BLOCK, 8) void rank1_attn_kernel(
    const float* __restrict__ x, float* __restrict__ y) {
    __shared__ float sx[N];

    const int b     = blockIdx.x / SLICES;
    const int slice = blockIdx.x % SLICES;
    const int tid   = threadIdx.x;

    const float* xb = x + b * N;

    // ---- stage row into LDS (coalesced float4) ----
    const float4* xb4 = reinterpret_cast<const float4*>(xb);
    float4* sx4 = reinterpret_cast<float4*>(sx);
#pragma unroll
    for (int k = 0; k < 2; ++k) sx4[tid + k * BLOCK] = xb4[tid + k * BLOCK];
    __syncthreads();

    const int iLocal = tid / SUBS;      // 0..31
    const int sub    = tid % SUBS;      // 0..7
    const int i      = slice * I_PER_BLOCK + iLocal;

    const float u8 = sx[i] * (1.0f / 128.0f);   // x_i / 128
    const v2f  t8  = {u8, u8};

    v2f den01 = {0.f, 0.f}, den23 = {0.f, 0.f};
    v2f num01 = {0.f, 0.f}, num23 = {0.f, 0.f};

    const v2f c5 = {1.f / 24.f, 1.f / 24.f};
    const v2f c4 = {1.f / 6.f,  1.f / 6.f};
    const v2f c3 = {0.5f, 0.5f};
    const v2f c1 = {1.0f, 1.0f};

    const float4* s4 = reinterpret_cast<const float4*>(sx);
    // j = jj*(SUBS*4) + sub*4 + {0..3}; jj in [0, 64) -> 256 j's per thread
#pragma unroll 8
    for (int jj = 0; jj < N / (SUBS * 4); ++jj) {
        float4 v = s4[jj * SUBS + sub];
        v2f v01 = {v.x, v.y};
        v2f v23 = {v.z, v.w};
        v2f u01 = t8 * v01;                 // v_pk_mul_f32
        v2f u23 = t8 * v23;
        v2f p01 = u01 * c5 + c4;            // v_pk_fma_f32 chain (deg-4)
        v2f p23 = u23 * c5 + c4;
        p01 = p01 * u01 + c3;  p23 = p23 * u23 + c3;
        p01 = p01 * u01 + c1;  p23 = p23 * u23 + c1;
        p01 = p01 * u01 + c1;  p23 = p23 * u23 + c1;
        p01 = p01 * p01;       p23 = p23 * p23;     // ^2
        p01 = p01 * p01;       p23 = p23 * p23;     // ^4
        p01 = p01 * p01;       p23 = p23 * p23;     // ^8
        den01 += p01;          den23 += p23;        // v_pk_add_f32
        num01 = p01 * v01 + num01;                  // v_pk_fma_f32
        num23 = p23 * v23 + num23;
    }
    float den = (den01.x + den01.y) + (den23.x + den23.y);
    float num = (num01.x + num01.y) + (num23.x + num23.y);

    // reduce across the 8 cooperating lanes (consecutive lanes in one wave)
    num += __shfl_xor(num, 1); den += __shfl_xor(den, 1);
    num += __shfl_xor(num, 2); den += __shfl_xor(den, 2);
    num += __shfl_xor(num, 4); den += __shfl_xor(den, 4);

    if (sub == 0) y[b * N + i] = num / den;
}

extern "C" void kernel_launch(void* const* d_in, const int* in_sizes, int n_in,
                              void* d_out, int out_size, void* d_ws, size_t ws_size,
                              hipStream_t stream) {
    const float* x = (const float*)d_in[0];
    float* y = (float*)d_out;
    dim3 grid(BATCH * SLICES);
    dim3 block(BLOCK);
    rank1_attn_kernel<<<grid, block, 0, stream>>>(x, y);
}

// Round 8
// 9.420 us; speedup vs baseline: 3.1217x; 3.1217x over previous
//
#include <hip/hip_runtime.h>

#define N 2048
#define BATCH 32
#define BLOCK 512
#define WAVES (BLOCK / 64)
#define NM 14           // moments M_1..M_14
#define KTERMS 14       // series terms t^0..t^13

// Rank-1 attention via moment expansion:
//   y_i = W(t_i)/Z(t_i),  t_i = x_i/16
//   Z(t) = sum_j e^{t x_j} = sum_k t^k/k! M_k      (M_k = sum_j x_j^k)
//   W(t) = Z'(t)          = sum_k t^k/k! M_{k+1}
// |t*x_j| <= ~1.3 -> 14-term Taylor remainder ~6e-11. O(B*N*K), no exp.
__global__ __launch_bounds__(BLOCK) void rank1_attn_kernel(
    const float* __restrict__ x, float* __restrict__ y) {
    __shared__ float smom[WAVES][NM];

    const int b    = blockIdx.x;
    const int tid  = threadIdx.x;
    const int lane = tid & 63;
    const int wv   = tid >> 6;

    // each thread owns one float4 of the row (512*4 = 2048)
    const float4 v = reinterpret_cast<const float4*>(x + b * N)[tid];
    const float xs[4] = {v.x, v.y, v.z, v.w};

    // ---- phase A: local moment partials M_1..M_14 ----
    float m[NM];
#pragma unroll
    for (int k = 0; k < NM; ++k) m[k] = 0.f;
#pragma unroll
    for (int e = 0; e < 4; ++e) {
        const float xe = xs[e];
        float p = xe;
#pragma unroll
        for (int k = 0; k < NM; ++k) { m[k] += p; p *= xe; }
    }

    // 64-lane butterfly reduce (all lanes end with wave total)
#pragma unroll
    for (int off = 1; off < 64; off <<= 1) {
#pragma unroll
        for (int k = 0; k < NM; ++k) m[k] += __shfl_xor(m[k], off);
    }
    if (lane == 0) {
#pragma unroll
        for (int k = 0; k < NM; ++k) smom[wv][k] = m[k];
    }
    __syncthreads();

    // ---- cross-wave sum -> row moments (uniform across block) ----
    float c[NM + 1];
    c[0] = (float)N;                 // M_0
#pragma unroll
    for (int k = 0; k < NM; ++k) {
        float s = 0.f;
#pragma unroll
        for (int w = 0; w < WAVES; ++w) s += smom[w][k];
        c[k + 1] = s;
    }

    const float invf[KTERMS] = {
        1.f, 1.f, 1.f / 2.f, 1.f / 6.f, 1.f / 24.f, 1.f / 120.f, 1.f / 720.f,
        1.f / 5040.f, 1.f / 40320.f, 1.f / 362880.f, 1.f / 3628800.f,
        1.f / 39916800.f, 1.f / 479001600.f, 1.f / 6227020800.f};
    float zc[KTERMS], wc[KTERMS];
#pragma unroll
    for (int k = 0; k < KTERMS; ++k) {
        zc[k] = c[k] * invf[k];      // M_k / k!
        wc[k] = c[k + 1] * invf[k];  // M_{k+1} / k!
    }

    // ---- phase B: two Horner evals per output ----
    float4 out;
    float* op = reinterpret_cast<float*>(&out);
#pragma unroll
    for (int e = 0; e < 4; ++e) {
        const float t = xs[e] * (1.0f / 16.0f);
        float zz = zc[KTERMS - 1];
        float ww = wc[KTERMS - 1];
#pragma unroll
        for (int k = KTERMS - 2; k >= 0; --k) {
            zz = zz * t + zc[k];
            ww = ww * t + wc[k];
        }
        op[e] = ww / zz;
    }
    reinterpret_cast<float4*>(y + b * N)[tid] = out;
}

extern "C" void kernel_launch(void* const* d_in, const int* in_sizes, int n_in,
                              void* d_out, int out_size, void* d_ws, size_t ws_size,
                              hipStream_t stream) {
    const float* x = (const float*)d_in[0];
    float* y = (float*)d_out;
    rank1_attn_kernel<<<dim3(BATCH), dim3(BLOCK), 0, stream>>>(x, y);
}